// Round 5
// baseline (421.592 us; speedup 1.0000x reference)
//
#include <hip/hip_runtime.h>
#include <hip/hip_cooperative_groups.h>
#include <cmath>

namespace cg = cooperative_groups;

// ---------------------------------------------------------------------------
// NeighborAdjustingLoss, single cooperative kernel:
//   phase 0: centrality rows (mem row-means)       -> cent[]
//   grid.sync()
//   phase 1: per-row top-k candidate select + loss -> per_row[]
//   phase 2: last-arriving block reduces per_row   -> out[0]
// B=4096 (sim BxB), M=8192 (mem BxM), k=32, fp32. Math identical to the
// validated round-1..4 kernels (absmax 0.0 vs reference).
// ---------------------------------------------------------------------------

#define CAP 256    // candidate capacity; expected ~93 for N(0,1) rows (>17 sigma)
#define MAXIT 40   // u32-key bisection bound (1 pass in practice)

__device__ inline float wave_max_f(float x) {
#pragma unroll
    for (int off = 32; off > 0; off >>= 1) x = fmaxf(x, __shfl_xor(x, off, 64));
    return x;
}
__device__ inline float wave_min_f(float x) {
#pragma unroll
    for (int off = 32; off > 0; off >>= 1) x = fminf(x, __shfl_xor(x, off, 64));
    return x;
}
__device__ inline float wave_sum_f(float x) {
#pragma unroll
    for (int off = 32; off > 0; off >>= 1) x += __shfl_xor(x, off, 64);
    return x;
}
__device__ inline unsigned int wave_min_u32(unsigned int x) {
#pragma unroll
    for (int off = 32; off > 0; off >>= 1) {
        unsigned int o = (unsigned int)__shfl_xor((int)x, off, 64);
        x = (o < x) ? o : x;
    }
    return x;
}

// order-preserving float<->uint key
__device__ inline unsigned int f_to_key(float f) {
    unsigned int u = __float_as_uint(f);
    return u ^ ((u & 0x80000000u) ? 0xFFFFFFFFu : 0x80000000u);
}
__device__ inline float key_to_f(unsigned int key) {
    unsigned int u = key ^ ((key & 0x80000000u) ? 0x80000000u : 0xFFFFFFFFu);
    return __uint_as_float(u);
}

// ---------------- shared row-loss body (device inline) ----------------
struct RowLossSmem {
    unsigned long long cand[CAP];
    unsigned long long s_sel[64];
    unsigned long long s_p33;
    unsigned int s_kmin[4];
    float s_cmin[4], s_cmax[4];
    unsigned int s_cnt;
    float s_diag;
    float s_red[4];
    int   s_last;
};

__device__ inline void row_loss_body(RowLossSmem& sm,
                                     const float* __restrict__ sim,
                                     const float* __restrict__ cent,
                                     float* __restrict__ per_row,
                                     int row, int B, int k, float temp) {
    const int tid = threadIdx.x, lane = tid & 63, wid = tid >> 6;

    // --- load row (float4-coalesced), order keys; diag -> key 0 ---
    unsigned int keys[16];
    unsigned int kmin = 0xFFFFFFFFu;
    const float4* rp = (const float4*)(sim + (size_t)row * B);
#pragma unroll
    for (int c = 0; c < 4; ++c) {
        float4 q = rp[c * 256 + tid];
        float t[4] = {q.x, q.y, q.z, q.w};
#pragma unroll
        for (int m = 0; m < 4; ++m) {
            const int j = c * 1024 + tid * 4 + m;
            unsigned int key = f_to_key(t[m]);
            if (j == row) { sm.s_diag = t[m]; key = 0u; }
            else if (key < kmin) kmin = key;
            keys[c * 4 + m] = key;
        }
    }
    { unsigned int w = wave_min_u32(kmin); if (lane == 0) sm.s_kmin[wid] = w; }
    if (tid == 0) { sm.s_cnt = 0; sm.s_p33 = ((unsigned long long)1u) << 32; }

    // --- fused pass: gather candidates (key > keyT) + cent min/max over rest.
    //     First-guess 2.0 puts count in [k+1, CAP] with huge margin for
    //     N(0,1) rows -> 1 pass; bisection fallback keeps it exact. ---
    unsigned int keyT = f_to_key(2.0f), loK = 0u, hiK = 0xFFFFFFFFu, cnt = 0;
    const unsigned int need = (unsigned int)k + 1u;
    const float4* cp = (const float4*)cent;
    for (int it = 0; it < MAXIT; ++it) {
        float cmin = INFINITY, cmax = -INFINITY;
        __syncthreads();                    // s_cnt (re)set + prior-row LDS safe
#pragma unroll
        for (int c = 0; c < 4; ++c) {
            float4 q = cp[c * 256 + tid];
            float t[4] = {q.x, q.y, q.z, q.w};
#pragma unroll
            for (int m = 0; m < 4; ++m) {
                const unsigned int key = keys[c * 4 + m];
                if (key == 0u) continue;    // diag: excluded everywhere
                if (key > keyT) {
                    const unsigned int pos = atomicAdd(&sm.s_cnt, 1u);
                    if (pos < CAP)
                        sm.cand[pos] = ((unsigned long long)key << 32) |
                                       (unsigned long long)(0xFFFFFFFFu -
                                           (unsigned int)(c * 1024 + tid * 4 + m));
                } else {
                    cmin = fminf(cmin, t[m]);
                    cmax = fmaxf(cmax, t[m]);
                }
            }
        }
        { float a = wave_min_f(cmin), b = wave_max_f(cmax);
          if (lane == 0) { sm.s_cmin[wid] = a; sm.s_cmax[wid] = b; } }
        __syncthreads();                    // cand/cnt/cmin/cmax visible
        cnt = sm.s_cnt;
        if (cnt >= need && cnt <= CAP) break;
        if (cnt < need) { hiK = keyT; keyT = loK + ((keyT - loK) >> 1); }
        else            { loK = keyT; keyT = keyT + ((hiK - keyT) >> 1); }
        if (tid == 0) sm.s_cnt = 0;
    }
    if (wid != 0) return;                   // waves 1-3: next row (barrier at top)

    // --- wave 0: exact all-pairs ranks, all state in named VGPRs ---
    const unsigned int n = min(cnt, (unsigned int)CAP);
    const unsigned int p0 = lane, p1 = lane + 64u, p2 = lane + 128u, p3 = lane + 192u;
    unsigned long long own0 = 0ull, own1 = 0ull, own2 = 0ull, own3 = 0ull;
    if (p0 < n) own0 = sm.cand[p0];
    if (p1 < n) own1 = sm.cand[p1];
    if (p2 < n) own2 = sm.cand[p2];
    if (p3 < n) own3 = sm.cand[p3];
    unsigned int r0 = 0, r1 = 0, r2 = 0, r3 = 0;
    const ulonglong2* c2 = (const ulonglong2*)sm.cand;   // broadcast b128 reads
    const unsigned int np = n >> 1;
    for (unsigned int o = 0; o < np; ++o) {
        ulonglong2 pr = c2[o];
        r0 += (pr.x > own0) ? 1u : 0u; r0 += (pr.y > own0) ? 1u : 0u;
        r1 += (pr.x > own1) ? 1u : 0u; r1 += (pr.y > own1) ? 1u : 0u;
        r2 += (pr.x > own2) ? 1u : 0u; r2 += (pr.y > own2) ? 1u : 0u;
        r3 += (pr.x > own3) ? 1u : 0u; r3 += (pr.y > own3) ? 1u : 0u;
    }
    if (n & 1u) {
        unsigned long long x = sm.cand[n - 1u];
        r0 += (x > own0) ? 1u : 0u; r1 += (x > own1) ? 1u : 0u;
        r2 += (x > own2) ? 1u : 0u; r3 += (x > own3) ? 1u : 0u;
    }
    float cmin2 = INFINITY, cmax2 = -INFINITY;
    const unsigned int uk = (unsigned int)k;
#define HANDLE(P, OWN, R)                                                     \
    if ((P) < n) {                                                            \
        if ((R) < uk) sm.s_sel[R] = (OWN);                                    \
        else if ((R) == uk) sm.s_p33 = (OWN);                                 \
        if ((R) >= uk) {                                                      \
            const int jj = (int)(0xFFFFFFFFu - (unsigned int)(OWN));          \
            const float cv = cent[jj];                                        \
            cmin2 = fminf(cmin2, cv);                                         \
            cmax2 = fmaxf(cmax2, cv);                                         \
        }                                                                     \
    }
    HANDLE(p0, own0, r0)
    HANDLE(p1, own1, r1)
    HANDLE(p2, own2, r2)
    HANDLE(p3, own3, r3)
#undef HANDLE
    __builtin_amdgcn_wave_barrier();   // order s_sel/s_p33 writes vs reads
    cmin2 = wave_min_f(cmin2);
    cmax2 = wave_max_f(cmax2);
    const float mn_c = fminf(cmin2,
        fminf(fminf(sm.s_cmin[0], sm.s_cmin[1]), fminf(sm.s_cmin[2], sm.s_cmin[3])));
    const float mx_c = fmaxf(cmax2,
        fmaxf(fmaxf(sm.s_cmax[0], sm.s_cmax[1]), fmaxf(sm.s_cmax[2], sm.s_cmax[3])));
    const unsigned int kminb =
        min(min(sm.s_kmin[0], sm.s_kmin[1]), min(sm.s_kmin[2], sm.s_kmin[3]));
    const float mn_s = key_to_f(kminb);
    const float mx_s = key_to_f((unsigned int)(sm.s_p33 >> 32));

    // --- finale (math identical to validated round-1..4 kernels) ---
    const float sdiag = sm.s_diag;
    const bool  act = (lane < k);
    const unsigned long long sel = act ? sm.s_sel[lane] : 0ull;
    const float sj = act ? key_to_f((unsigned int)(sel >> 32)) : -INFINITY;
    const int   j  = act ? (int)(0xFFFFFFFFu - (unsigned int)sel) : 0;
    const float cj = cent[j];

    float a = -INFINITY;
    if (act) {
        const float ns = (sj - mn_s) / (mx_s - mn_s);
        const float nc = (cj - mn_c) / (mx_c - mn_c);
        a = (ns - nc) * temp;
    }
    const float am   = wave_max_f(a);
    const float e    = act ? expf(a - am) : 0.0f;
    const float esum = wave_sum_f(e);
    const float pw   = e / esum;

    const float m2  = fmaxf(wave_max_f(sj), sdiag);
    const float ex  = act ? expf(sj - m2) : 0.0f;
    const float lse = m2 + logf(wave_sum_f(ex) + expf(sdiag - m2));

    const float num = wave_sum_f(act ? pw * (sj - lse) : 0.0f) + (sdiag - lse);
    const float den = 1.0f + wave_sum_f(pw);
    if (lane == 0) per_row[row] = -num / den;
}

// ---------------- device helper: centrality of one row ----------------
__device__ inline void cent_row(const float* __restrict__ mem,
                                float* __restrict__ cent, int row, int M,
                                float* s4) {
    const float4* p = (const float4*)(mem + (size_t)row * M);
    const int n4 = M >> 2;
    float acc = 0.0f;
    int i = threadIdx.x;
    for (; i + 1792 < n4; i += 2048) {
        float4 q0 = p[i], q1 = p[i + 256], q2 = p[i + 512], q3 = p[i + 768];
        float4 q4 = p[i + 1024], q5 = p[i + 1280], q6 = p[i + 1536], q7 = p[i + 1792];
        acc += ((q0.x + q0.y) + (q0.z + q0.w)) + ((q1.x + q1.y) + (q1.z + q1.w))
             + ((q2.x + q2.y) + (q2.z + q2.w)) + ((q3.x + q3.y) + (q3.z + q3.w))
             + ((q4.x + q4.y) + (q4.z + q4.w)) + ((q5.x + q5.y) + (q5.z + q5.w))
             + ((q6.x + q6.y) + (q6.z + q6.w)) + ((q7.x + q7.y) + (q7.z + q7.w));
    }
    for (; i < n4; i += 256) {
        float4 q = p[i];
        acc += (q.x + q.y) + (q.z + q.w);
    }
    acc = wave_sum_f(acc);
    const int lane = threadIdx.x & 63, wid = threadIdx.x >> 6;
    if (lane == 0) s4[wid] = acc;
    __syncthreads();
    if (threadIdx.x == 0) cent[row] = (s4[0] + s4[1] + s4[2] + s4[3]) / (float)M;
    __syncthreads();
}

// ---------------- fused cooperative kernel ----------------
__global__ __launch_bounds__(256)
void fused_kernel(const float* __restrict__ sim, const float* __restrict__ mem,
                  const int* __restrict__ knn, const float* __restrict__ temp_p,
                  float* __restrict__ cent, float* __restrict__ per_row,
                  unsigned int* __restrict__ done, float* __restrict__ out,
                  int B, int M) {
    cg::grid_group grid = cg::this_grid();
    __shared__ RowLossSmem sm;
    const int tid = threadIdx.x;
    const int G = gridDim.x;
    const int k = knn[0];
    const float temp = temp_p[0];

    // phase 0: centrality rows (strided)
    for (int row = blockIdx.x; row < B; row += G)
        cent_row(mem, cent, row, M, sm.s_red);
    if (blockIdx.x == 0 && tid == 0) *done = 0u;  // ws is poisoned; init counter
    grid.sync();

    // phase 1: row losses (strided); barrier inside body protects LDS reuse
    for (int row = blockIdx.x; row < B; row += G)
        row_loss_body(sm, sim, cent, per_row, row, B, k, temp);

    // phase 2: last-arriving block reduces per_row -> out[0]
    __syncthreads();
    if (tid == 0) {
        __threadfence();
        sm.s_last = (atomicAdd(done, 1u) == (unsigned int)G - 1u) ? 1 : 0;
    }
    __syncthreads();
    if (sm.s_last) {
        __threadfence();
        float acc = 0.0f;
        const float4* p = (const float4*)per_row;
        const int n4 = B >> 2;
        for (int i = tid; i < n4; i += 256) {
            float4 q = p[i];
            acc += (q.x + q.y) + (q.z + q.w);
        }
        acc = wave_sum_f(acc);
        const int lane = tid & 63, wid = tid >> 6;
        if (lane == 0) sm.s_red[wid] = acc;
        __syncthreads();
        if (tid == 0)
            out[0] = (sm.s_red[0] + sm.s_red[1] + sm.s_red[2] + sm.s_red[3]) / (float)B;
    }
}

// ---------------- fallback (round-4 validated 3-kernel path) ----------------
__global__ __launch_bounds__(256)
void cent_kernel(const float* __restrict__ mem, float* __restrict__ cent, int M) {
    __shared__ float s[4];
    cent_row(mem, cent, blockIdx.x, M, s);
}
__global__ __launch_bounds__(256)
void row_loss_kernel(const float* __restrict__ sim, const float* __restrict__ cent,
                     const int* __restrict__ knn, const float* __restrict__ temp_p,
                     float* __restrict__ per_row, int B) {
    __shared__ RowLossSmem sm;
    row_loss_body(sm, sim, cent, per_row, blockIdx.x, B, knn[0], temp_p[0]);
}
__global__ __launch_bounds__(256)
void reduce_kernel(const float* __restrict__ per_row, float* __restrict__ out, int B) {
    __shared__ float s[4];
    float acc = 0.0f;
    const float4* p = (const float4*)per_row;
    const int n4 = B >> 2;
    for (int i = threadIdx.x; i < n4; i += 256) {
        float4 q = p[i];
        acc += (q.x + q.y) + (q.z + q.w);
    }
    acc = wave_sum_f(acc);
    const int lane = threadIdx.x & 63, wid = threadIdx.x >> 6;
    if (lane == 0) s[wid] = acc;
    __syncthreads();
    if (threadIdx.x == 0) out[0] = (s[0] + s[1] + s[2] + s[3]) / (float)B;
}

extern "C" void kernel_launch(void* const* d_in, const int* in_sizes, int n_in,
                              void* d_out, int out_size, void* d_ws, size_t ws_size,
                              hipStream_t stream) {
    const float* sim  = (const float*)d_in[0];
    const float* mem  = (const float*)d_in[1];
    const int*   knn  = (const int*)d_in[2];
    const float* temp = (const float*)d_in[3];
    float* out     = (float*)d_out;
    float* cent    = (float*)d_ws;                        // B floats
    float* per_row = (float*)d_ws + 4096;                 // B floats
    unsigned int* done = (unsigned int*)((float*)d_ws + 8192);

    int B = (int)(std::sqrt((double)in_sizes[0]) + 0.5);
    int M = in_sizes[1] / B;

    // occupancy-adaptive cooperative grid (host-side queries: capture-safe,
    // zero replay cost — graph replays only the device work)
    int perCU = 0;
    (void)hipOccupancyMaxActiveBlocksPerMultiprocessor(
        &perCU, (const void*)fused_kernel, 256, 0);
    int nCU = 0, dev = 0;
    (void)hipGetDevice(&dev);
    (void)hipDeviceGetAttribute(&nCU, hipDeviceAttributeMultiprocessorCount, dev);
    if (nCU <= 0) nCU = 256;
    int G = (perCU > 0) ? perCU * nCU : nCU;
    if (G > B) G = B;

    void* args[] = {(void*)&sim, (void*)&mem, (void*)&knn, (void*)&temp,
                    (void*)&cent, (void*)&per_row, (void*)&done, (void*)&out,
                    (void*)&B, (void*)&M};
    hipError_t err = hipLaunchCooperativeKernel(
        (const void*)fused_kernel, dim3(G), dim3(256), args, 0, stream);
    if (err != hipSuccess) {
        // fallback: validated 3-kernel path
        cent_kernel<<<B, 256, 0, stream>>>(mem, cent, M);
        row_loss_kernel<<<B, 256, 0, stream>>>(sim, cent, knn, temp, per_row, B);
        reduce_kernel<<<1, 256, 0, stream>>>(per_row, out, B);
    }
}

// Round 6
// 322.948 us; speedup vs baseline: 1.3054x; 1.3054x over previous
//
#include <hip/hip_runtime.h>
#include <cmath>

// ---------------------------------------------------------------------------
// NeighborAdjustingLoss, 2 dispatches (no cooperative launch — round 5 showed
// co-residency-capped grids + grid.sync regress 4x vs oversubscribed blocks):
//   D1 prep (2B blocks): [0,B)  per-row candidate select -> hdr + candG
//                        [B,2B) centrality row-means     -> cent
//        (independent halves overlap inside one dispatch)
//   D2 loss (B blocks):  bitmask cent-min/max + all-pairs rank + finale
//                        -> per_row; last-arriving block reduces -> out[0]
// B=4096 (sim BxB), M=8192 (mem BxM), k=32, fp32. Finale math identical to
// the validated round-1..4 kernels (absmax 0.0 vs reference every round).
// ---------------------------------------------------------------------------

#define CAP 256    // candidate capacity; expected ~93 for N(0,1) rows (>17 sigma)
#define MAXIT 40   // u32-key bisection bound (1 pass in practice)

__device__ inline float wave_max_f(float x) {
#pragma unroll
    for (int off = 32; off > 0; off >>= 1) x = fmaxf(x, __shfl_xor(x, off, 64));
    return x;
}
__device__ inline float wave_min_f(float x) {
#pragma unroll
    for (int off = 32; off > 0; off >>= 1) x = fminf(x, __shfl_xor(x, off, 64));
    return x;
}
__device__ inline float wave_sum_f(float x) {
#pragma unroll
    for (int off = 32; off > 0; off >>= 1) x += __shfl_xor(x, off, 64);
    return x;
}
__device__ inline unsigned int wave_min_u32(unsigned int x) {
#pragma unroll
    for (int off = 32; off > 0; off >>= 1) {
        unsigned int o = (unsigned int)__shfl_xor((int)x, off, 64);
        x = (o < x) ? o : x;
    }
    return x;
}
__device__ inline unsigned int wave_sum_u32(unsigned int x) {
#pragma unroll
    for (int off = 32; off > 0; off >>= 1) x += (unsigned int)__shfl_xor((int)x, off, 64);
    return x;
}

// order-preserving float<->uint key
__device__ inline unsigned int f_to_key(float f) {
    unsigned int u = __float_as_uint(f);
    return u ^ ((u & 0x80000000u) ? 0xFFFFFFFFu : 0x80000000u);
}
__device__ inline float key_to_f(unsigned int key) {
    unsigned int u = key ^ ((key & 0x80000000u) ? 0x80000000u : 0xFFFFFFFFu);
    return __uint_as_float(u);
}

// ---------------- D1: prep (candidate select || centrality) ----------------
struct PrepSmem {
    __align__(16) unsigned long long cand[CAP];
    unsigned int s_red[4];
    unsigned int s_kmin[4];
    unsigned int s_cnt;
    float s_diag;
    float s4[4];
};

__device__ inline void cent_row(const float* __restrict__ mem,
                                float* __restrict__ cent, int row, int M,
                                float* s4) {
    const float4* p = (const float4*)(mem + (size_t)row * M);
    const int n4 = M >> 2;
    float acc = 0.0f;
    int i = threadIdx.x;
    for (; i + 1792 < n4; i += 2048) {
        float4 q0 = p[i], q1 = p[i + 256], q2 = p[i + 512], q3 = p[i + 768];
        float4 q4 = p[i + 1024], q5 = p[i + 1280], q6 = p[i + 1536], q7 = p[i + 1792];
        acc += ((q0.x + q0.y) + (q0.z + q0.w)) + ((q1.x + q1.y) + (q1.z + q1.w))
             + ((q2.x + q2.y) + (q2.z + q2.w)) + ((q3.x + q3.y) + (q3.z + q3.w))
             + ((q4.x + q4.y) + (q4.z + q4.w)) + ((q5.x + q5.y) + (q5.z + q5.w))
             + ((q6.x + q6.y) + (q6.z + q6.w)) + ((q7.x + q7.y) + (q7.z + q7.w));
    }
    for (; i < n4; i += 256) {
        float4 q = p[i];
        acc += (q.x + q.y) + (q.z + q.w);
    }
    acc = wave_sum_f(acc);
    const int lane = threadIdx.x & 63, wid = threadIdx.x >> 6;
    if (lane == 0) s4[wid] = acc;
    __syncthreads();
    if (threadIdx.x == 0) cent[row] = (s4[0] + s4[1] + s4[2] + s4[3]) / (float)M;
}

__global__ __launch_bounds__(256)
void prep_kernel(const float* __restrict__ sim, const float* __restrict__ mem,
                 const int* __restrict__ knn,
                 float* __restrict__ cent, uint4* __restrict__ hdr,
                 unsigned long long* __restrict__ candG,
                 unsigned int* __restrict__ done, int B, int M) {
    __shared__ PrepSmem sm;
    const int tid = threadIdx.x, lane = tid & 63, wid = tid >> 6;
    const int bid = blockIdx.x;

    if (bid >= B) {                         // ---- centrality half ----
        cent_row(mem, cent, bid - B, M, sm.s4);
        return;
    }

    // ---- candidate-select half (row = bid) ----
    const int row = bid;
    if (row == 0 && tid == 0) *done = 0u;   // init last-arrive counter for D2
    const int k = knn[0];

    // load row (float4-coalesced), order keys; diag -> key 0
    unsigned int keys[16];
    unsigned int kmin = 0xFFFFFFFFu;
    const float4* rp = (const float4*)(sim + (size_t)row * B);
#pragma unroll
    for (int c = 0; c < 4; ++c) {
        float4 q = rp[c * 256 + tid];
        float t[4] = {q.x, q.y, q.z, q.w};
#pragma unroll
        for (int m = 0; m < 4; ++m) {
            const int j = c * 1024 + tid * 4 + m;
            unsigned int key = f_to_key(t[m]);
            if (j == row) { sm.s_diag = t[m]; key = 0u; }
            else if (key < kmin) kmin = key;
            keys[c * 4 + m] = key;
        }
    }
    { unsigned int w = wave_min_u32(kmin); if (lane == 0) sm.s_kmin[wid] = w; }
    if (tid == 0) sm.s_cnt = 0;

    // bisect threshold: count(key > keyT) in [k+1, CAP]; first guess 2.0
    // converges in 1 pass for N(0,1) rows, bisection keeps it exact otherwise
    unsigned int keyT = f_to_key(2.0f), loK = 0u, hiK = 0xFFFFFFFFu, cnt = 0;
    const unsigned int need = (unsigned int)k + 1u;
    for (int it = 0; it < MAXIT; ++it) {
        unsigned int cl = 0;
#pragma unroll
        for (int i = 0; i < 16; ++i) cl += (keys[i] > keyT) ? 1u : 0u;
        unsigned int ws = wave_sum_u32(cl);
        __syncthreads();                    // protect s_red reuse
        if (lane == 0) sm.s_red[wid] = ws;
        __syncthreads();
        cnt = sm.s_red[0] + sm.s_red[1] + sm.s_red[2] + sm.s_red[3];
        if (cnt >= need && cnt <= CAP) break;
        if (cnt < need) { hiK = keyT; keyT = loK + ((keyT - loK) >> 1); }
        else            { loK = keyT; keyT = keyT + ((hiK - keyT) >> 1); }
    }

    // gather candidates (packed key:~idx) into LDS
#pragma unroll
    for (int c = 0; c < 4; ++c) {
#pragma unroll
        for (int m = 0; m < 4; ++m) {
            const unsigned int key = keys[c * 4 + m];
            if (key > keyT) {               // diag key 0 never passes
                const unsigned int pos = atomicAdd(&sm.s_cnt, 1u);
                if (pos < CAP)
                    sm.cand[pos] = ((unsigned long long)key << 32) |
                                   (unsigned long long)(0xFFFFFFFFu -
                                       (unsigned int)(c * 1024 + tid * 4 + m));
            }
        }
    }
    __syncthreads();
    const unsigned int n = min(sm.s_cnt, (unsigned int)CAP);
    if ((unsigned int)tid < n) candG[(size_t)row * CAP + tid] = sm.cand[tid];
    if (tid == 0) {
        const unsigned int km =
            min(min(sm.s_kmin[0], sm.s_kmin[1]), min(sm.s_kmin[2], sm.s_kmin[3]));
        hdr[row] = make_uint4(n, km, __float_as_uint(sm.s_diag), 0u);
    }
}

// ---------------- D2: loss (bitmask cent-scan + rank + finale) ----------------
struct LossSmem {
    __align__(16) unsigned long long cand[CAP];
    unsigned long long s_sel[64];
    unsigned long long s_p33;
    unsigned int mask[128];                 // 4096-bit exclusion mask
    float s_cmin[4], s_cmax[4];
    float s_red[4];
    int   s_last;
};

__global__ __launch_bounds__(256)
void loss_kernel(const float* __restrict__ cent, const uint4* __restrict__ hdr,
                 const unsigned long long* __restrict__ candG,
                 const int* __restrict__ knn, const float* __restrict__ temp_p,
                 float* __restrict__ per_row, unsigned int* __restrict__ done,
                 float* __restrict__ out, int B) {
    __shared__ LossSmem sm;
    const int tid = threadIdx.x, lane = tid & 63, wid = tid >> 6;
    const int row = blockIdx.x;
    const int k = knn[0];
    const float temp = temp_p[0];

    const uint4 h = hdr[row];
    const unsigned int n = min(h.x, (unsigned int)CAP);
    const float sdiag = __uint_as_float(h.z);

    // load candidates to LDS; zero bitmask
    if ((unsigned int)tid < n) sm.cand[tid] = candG[(size_t)row * CAP + tid];
    if (tid < 128) sm.mask[tid] = 0u;
    if (tid == 0) sm.s_p33 = ((unsigned long long)1u) << 32;
    __syncthreads();
    if ((unsigned int)tid < n) {
        const int idx = (int)(0xFFFFFFFFu - (unsigned int)sm.cand[tid]);
        atomicOr(&sm.mask[idx >> 5], 1u << (idx & 31));
    }
    if (tid == 0) atomicOr(&sm.mask[row >> 5], 1u << (row & 31));
    __syncthreads();

    // scan cent[] (16 KB, L1-hot: identical vector for all rows) with exclusion
    float cmin = INFINITY, cmax = -INFINITY;
    const float4* cp = (const float4*)cent;
#pragma unroll
    for (int c = 0; c < 4; ++c) {
        float4 q = cp[c * 256 + tid];
        const unsigned int mw = sm.mask[c * 32 + (tid >> 3)];  // broadcast read
        float t[4] = {q.x, q.y, q.z, q.w};
#pragma unroll
        for (int m = 0; m < 4; ++m) {
            const unsigned int bit = 1u << (((tid & 7) << 2) + m);
            if (!(mw & bit)) { cmin = fminf(cmin, t[m]); cmax = fmaxf(cmax, t[m]); }
        }
    }
    { float a = wave_min_f(cmin), b = wave_max_f(cmax);
      if (lane == 0) { sm.s_cmin[wid] = a; sm.s_cmax[wid] = b; } }
    __syncthreads();

    if (wid == 0) {
        // exact all-pairs ranks, all state in named VGPRs (validated round 4)
        const unsigned int p0 = lane, p1 = lane + 64u, p2 = lane + 128u, p3 = lane + 192u;
        unsigned long long own0 = 0ull, own1 = 0ull, own2 = 0ull, own3 = 0ull;
        if (p0 < n) own0 = sm.cand[p0];
        if (p1 < n) own1 = sm.cand[p1];
        if (p2 < n) own2 = sm.cand[p2];
        if (p3 < n) own3 = sm.cand[p3];
        unsigned int r0 = 0, r1 = 0, r2 = 0, r3 = 0;
        const ulonglong2* c2 = (const ulonglong2*)sm.cand;     // broadcast b128
        const unsigned int np = n >> 1;
        for (unsigned int o = 0; o < np; ++o) {
            ulonglong2 pr = c2[o];
            r0 += (pr.x > own0) ? 1u : 0u; r0 += (pr.y > own0) ? 1u : 0u;
            r1 += (pr.x > own1) ? 1u : 0u; r1 += (pr.y > own1) ? 1u : 0u;
            r2 += (pr.x > own2) ? 1u : 0u; r2 += (pr.y > own2) ? 1u : 0u;
            r3 += (pr.x > own3) ? 1u : 0u; r3 += (pr.y > own3) ? 1u : 0u;
        }
        if (n & 1u) {
            unsigned long long x = sm.cand[n - 1u];
            r0 += (x > own0) ? 1u : 0u; r1 += (x > own1) ? 1u : 0u;
            r2 += (x > own2) ? 1u : 0u; r3 += (x > own3) ? 1u : 0u;
        }
        float cmin2 = INFINITY, cmax2 = -INFINITY;
        const unsigned int uk = (unsigned int)k;
#define HANDLE(P, OWN, R)                                                     \
        if ((P) < n) {                                                        \
            if ((R) < uk) sm.s_sel[R] = (OWN);                                \
            else if ((R) == uk) sm.s_p33 = (OWN);                             \
            if ((R) >= uk) {                                                  \
                const int jj = (int)(0xFFFFFFFFu - (unsigned int)(OWN));      \
                const float cv = cent[jj];                                    \
                cmin2 = fminf(cmin2, cv);                                     \
                cmax2 = fmaxf(cmax2, cv);                                     \
            }                                                                 \
        }
        HANDLE(p0, own0, r0)
        HANDLE(p1, own1, r1)
        HANDLE(p2, own2, r2)
        HANDLE(p3, own3, r3)
#undef HANDLE
        __builtin_amdgcn_wave_barrier();   // order s_sel/s_p33 writes vs reads
        cmin2 = wave_min_f(cmin2);
        cmax2 = wave_max_f(cmax2);
        const float mn_c = fminf(cmin2,
            fminf(fminf(sm.s_cmin[0], sm.s_cmin[1]), fminf(sm.s_cmin[2], sm.s_cmin[3])));
        const float mx_c = fmaxf(cmax2,
            fmaxf(fmaxf(sm.s_cmax[0], sm.s_cmax[1]), fmaxf(sm.s_cmax[2], sm.s_cmax[3])));
        const float mn_s = key_to_f(h.y);
        const float mx_s = key_to_f((unsigned int)(sm.s_p33 >> 32));

        // finale (math identical to validated round-1..4 kernels)
        const bool  act = (lane < k);
        const unsigned long long sel = act ? sm.s_sel[lane] : 0ull;
        const float sj = act ? key_to_f((unsigned int)(sel >> 32)) : -INFINITY;
        const int   j  = act ? (int)(0xFFFFFFFFu - (unsigned int)sel) : 0;
        const float cj = cent[j];

        float a = -INFINITY;
        if (act) {
            const float ns = (sj - mn_s) / (mx_s - mn_s);
            const float nc = (cj - mn_c) / (mx_c - mn_c);
            a = (ns - nc) * temp;
        }
        const float am   = wave_max_f(a);
        const float e    = act ? expf(a - am) : 0.0f;
        const float esum = wave_sum_f(e);
        const float pw   = e / esum;

        const float m2  = fmaxf(wave_max_f(sj), sdiag);
        const float ex  = act ? expf(sj - m2) : 0.0f;
        const float lse = m2 + logf(wave_sum_f(ex) + expf(sdiag - m2));

        const float num = wave_sum_f(act ? pw * (sj - lse) : 0.0f) + (sdiag - lse);
        const float den = 1.0f + wave_sum_f(pw);
        if (lane == 0) per_row[row] = -num / den;
    }

    // last-arriving block reduces per_row -> out[0]
    __syncthreads();
    if (tid == 0) {
        __threadfence();
        sm.s_last = (atomicAdd(done, 1u) == (unsigned int)gridDim.x - 1u) ? 1 : 0;
    }
    __syncthreads();
    if (sm.s_last) {
        __threadfence();
        float acc = 0.0f;
        const float4* p = (const float4*)per_row;
        const int n4 = B >> 2;
        for (int i = tid; i < n4; i += 256) {
            float4 q = p[i];
            acc += (q.x + q.y) + (q.z + q.w);
        }
        acc = wave_sum_f(acc);
        if (lane == 0) sm.s_red[wid] = acc;
        __syncthreads();
        if (tid == 0)
            out[0] = (sm.s_red[0] + sm.s_red[1] + sm.s_red[2] + sm.s_red[3]) / (float)B;
    }
}

extern "C" void kernel_launch(void* const* d_in, const int* in_sizes, int n_in,
                              void* d_out, int out_size, void* d_ws, size_t ws_size,
                              hipStream_t stream) {
    const float* sim  = (const float*)d_in[0];
    const float* mem  = (const float*)d_in[1];
    const int*   knn  = (const int*)d_in[2];
    const float* temp = (const float*)d_in[3];
    float* out = (float*)d_out;

    // ws layout: cent[4096]f @0 | per_row[4096]f @16K | done @32K |
    //            hdr[4096]uint4 @40K | candG[4096*CAP]u64 @104K (~8 MB)
    char* base = (char*)d_ws;
    float* cent    = (float*)base;
    float* per_row = (float*)(base + 16384);
    unsigned int* done = (unsigned int*)(base + 32768);
    uint4* hdr = (uint4*)(base + 40960);
    unsigned long long* candG = (unsigned long long*)(base + 40960 + 65536);

    const int B = (int)(std::sqrt((double)in_sizes[0]) + 0.5);
    const int M = in_sizes[1] / B;

    prep_kernel<<<2 * B, 256, 0, stream>>>(sim, mem, knn, cent, hdr, candG, done, B, M);
    loss_kernel<<<B, 256, 0, stream>>>(cent, hdr, candG, knn, temp, per_row, done, out, B);
}

// Round 7
// 257.788 us; speedup vs baseline: 1.6354x; 1.2528x over previous
//
#include <hip/hip_runtime.h>
#include <cmath>

// ---------------------------------------------------------------------------
// NeighborAdjustingLoss, 3 dispatches:
//   D1 prep (2B blocks): [0,B)  per-row candidate select -> hdr + candG
//                        [B,2B) centrality row-means     -> cent
//        (independent halves overlap inside one dispatch)
//   D2 loss (B blocks):  bitmask cent-min/max + all-pairs rank + finale -> per_row
//   D3 reduce (1 block): mean(per_row) -> out[0]
// NOTE: no __threadfence / last-arriving-block pattern — on CDNA4 device-scope
// fences force per-XCD L2 writeback/invalidate; 4096 of them serialized the
// grid (round 6: loss_kernel 92 us at 13% VALU / 0.3% HBM). A 1-block reduce
// dispatch is ~4 us and fence-free.
// B=4096 (sim BxB), M=8192 (mem BxM), k=32, fp32. Math identical to the
// validated round-1..4 kernels (absmax 0.0 vs reference every round).
// ---------------------------------------------------------------------------

#define CAP 256    // candidate capacity; expected ~93 for N(0,1) rows (>17 sigma)
#define MAXIT 40   // u32-key bisection bound (1 pass in practice)

__device__ inline float wave_max_f(float x) {
#pragma unroll
    for (int off = 32; off > 0; off >>= 1) x = fmaxf(x, __shfl_xor(x, off, 64));
    return x;
}
__device__ inline float wave_min_f(float x) {
#pragma unroll
    for (int off = 32; off > 0; off >>= 1) x = fminf(x, __shfl_xor(x, off, 64));
    return x;
}
__device__ inline float wave_sum_f(float x) {
#pragma unroll
    for (int off = 32; off > 0; off >>= 1) x += __shfl_xor(x, off, 64);
    return x;
}
__device__ inline unsigned int wave_min_u32(unsigned int x) {
#pragma unroll
    for (int off = 32; off > 0; off >>= 1) {
        unsigned int o = (unsigned int)__shfl_xor((int)x, off, 64);
        x = (o < x) ? o : x;
    }
    return x;
}
__device__ inline unsigned int wave_sum_u32(unsigned int x) {
#pragma unroll
    for (int off = 32; off > 0; off >>= 1) x += (unsigned int)__shfl_xor((int)x, off, 64);
    return x;
}

// order-preserving float<->uint key
__device__ inline unsigned int f_to_key(float f) {
    unsigned int u = __float_as_uint(f);
    return u ^ ((u & 0x80000000u) ? 0xFFFFFFFFu : 0x80000000u);
}
__device__ inline float key_to_f(unsigned int key) {
    unsigned int u = key ^ ((key & 0x80000000u) ? 0x80000000u : 0xFFFFFFFFu);
    return __uint_as_float(u);
}

// ---------------- D1: prep (candidate select || centrality) ----------------
struct PrepSmem {
    __align__(16) unsigned long long cand[CAP];
    unsigned int s_red[4];
    unsigned int s_kmin[4];
    unsigned int s_cnt;
    float s_diag;
    float s4[4];
};

__device__ inline void cent_row(const float* __restrict__ mem,
                                float* __restrict__ cent, int row, int M,
                                float* s4) {
    const float4* p = (const float4*)(mem + (size_t)row * M);
    const int n4 = M >> 2;
    float acc = 0.0f;
    int i = threadIdx.x;
    for (; i + 1792 < n4; i += 2048) {
        float4 q0 = p[i], q1 = p[i + 256], q2 = p[i + 512], q3 = p[i + 768];
        float4 q4 = p[i + 1024], q5 = p[i + 1280], q6 = p[i + 1536], q7 = p[i + 1792];
        acc += ((q0.x + q0.y) + (q0.z + q0.w)) + ((q1.x + q1.y) + (q1.z + q1.w))
             + ((q2.x + q2.y) + (q2.z + q2.w)) + ((q3.x + q3.y) + (q3.z + q3.w))
             + ((q4.x + q4.y) + (q4.z + q4.w)) + ((q5.x + q5.y) + (q5.z + q5.w))
             + ((q6.x + q6.y) + (q6.z + q6.w)) + ((q7.x + q7.y) + (q7.z + q7.w));
    }
    for (; i < n4; i += 256) {
        float4 q = p[i];
        acc += (q.x + q.y) + (q.z + q.w);
    }
    acc = wave_sum_f(acc);
    const int lane = threadIdx.x & 63, wid = threadIdx.x >> 6;
    if (lane == 0) s4[wid] = acc;
    __syncthreads();
    if (threadIdx.x == 0) cent[row] = (s4[0] + s4[1] + s4[2] + s4[3]) / (float)M;
}

__global__ __launch_bounds__(256)
void prep_kernel(const float* __restrict__ sim, const float* __restrict__ mem,
                 const int* __restrict__ knn,
                 float* __restrict__ cent, uint4* __restrict__ hdr,
                 unsigned long long* __restrict__ candG, int B, int M) {
    __shared__ PrepSmem sm;
    const int tid = threadIdx.x, lane = tid & 63, wid = tid >> 6;
    const int bid = blockIdx.x;

    if (bid >= B) {                         // ---- centrality half ----
        cent_row(mem, cent, bid - B, M, sm.s4);
        return;
    }

    // ---- candidate-select half (row = bid) ----
    const int row = bid;
    const int k = knn[0];

    // load row (float4-coalesced), order keys; diag -> key 0
    unsigned int keys[16];
    unsigned int kmin = 0xFFFFFFFFu;
    const float4* rp = (const float4*)(sim + (size_t)row * B);
#pragma unroll
    for (int c = 0; c < 4; ++c) {
        float4 q = rp[c * 256 + tid];
        float t[4] = {q.x, q.y, q.z, q.w};
#pragma unroll
        for (int m = 0; m < 4; ++m) {
            const int j = c * 1024 + tid * 4 + m;
            unsigned int key = f_to_key(t[m]);
            if (j == row) { sm.s_diag = t[m]; key = 0u; }
            else if (key < kmin) kmin = key;
            keys[c * 4 + m] = key;
        }
    }
    { unsigned int w = wave_min_u32(kmin); if (lane == 0) sm.s_kmin[wid] = w; }
    if (tid == 0) sm.s_cnt = 0;

    // bisect threshold: count(key > keyT) in [k+1, CAP]; first guess 2.0
    // converges in 1 pass for N(0,1) rows, bisection keeps it exact otherwise
    unsigned int keyT = f_to_key(2.0f), loK = 0u, hiK = 0xFFFFFFFFu, cnt = 0;
    const unsigned int need = (unsigned int)k + 1u;
    for (int it = 0; it < MAXIT; ++it) {
        unsigned int cl = 0;
#pragma unroll
        for (int i = 0; i < 16; ++i) cl += (keys[i] > keyT) ? 1u : 0u;
        unsigned int ws = wave_sum_u32(cl);
        __syncthreads();                    // protect s_red reuse
        if (lane == 0) sm.s_red[wid] = ws;
        __syncthreads();
        cnt = sm.s_red[0] + sm.s_red[1] + sm.s_red[2] + sm.s_red[3];
        if (cnt >= need && cnt <= CAP) break;
        if (cnt < need) { hiK = keyT; keyT = loK + ((keyT - loK) >> 1); }
        else            { loK = keyT; keyT = keyT + ((hiK - keyT) >> 1); }
    }

    // gather candidates (packed key:~idx) into LDS
#pragma unroll
    for (int c = 0; c < 4; ++c) {
#pragma unroll
        for (int m = 0; m < 4; ++m) {
            const unsigned int key = keys[c * 4 + m];
            if (key > keyT) {               // diag key 0 never passes
                const unsigned int pos = atomicAdd(&sm.s_cnt, 1u);
                if (pos < CAP)
                    sm.cand[pos] = ((unsigned long long)key << 32) |
                                   (unsigned long long)(0xFFFFFFFFu -
                                       (unsigned int)(c * 1024 + tid * 4 + m));
            }
        }
    }
    __syncthreads();
    const unsigned int n = min(sm.s_cnt, (unsigned int)CAP);
    if ((unsigned int)tid < n) candG[(size_t)row * CAP + tid] = sm.cand[tid];
    if (tid == 0) {
        const unsigned int km =
            min(min(sm.s_kmin[0], sm.s_kmin[1]), min(sm.s_kmin[2], sm.s_kmin[3]));
        hdr[row] = make_uint4(n, km, __float_as_uint(sm.s_diag), 0u);
    }
}

// ---------------- D2: loss (bitmask cent-scan + rank + finale) ----------------
struct LossSmem {
    __align__(16) unsigned long long cand[CAP];
    unsigned long long s_sel[64];
    unsigned long long s_p33;
    unsigned int mask[128];                 // 4096-bit exclusion mask
    float s_cmin[4], s_cmax[4];
};

__global__ __launch_bounds__(256)
void loss_kernel(const float* __restrict__ cent, const uint4* __restrict__ hdr,
                 const unsigned long long* __restrict__ candG,
                 const int* __restrict__ knn, const float* __restrict__ temp_p,
                 float* __restrict__ per_row, int B) {
    __shared__ LossSmem sm;
    const int tid = threadIdx.x, lane = tid & 63, wid = tid >> 6;
    const int row = blockIdx.x;
    const int k = knn[0];
    const float temp = temp_p[0];

    const uint4 h = hdr[row];
    const unsigned int n = min(h.x, (unsigned int)CAP);
    const float sdiag = __uint_as_float(h.z);

    // load candidates to LDS; zero bitmask
    if ((unsigned int)tid < n) sm.cand[tid] = candG[(size_t)row * CAP + tid];
    if (tid < 128) sm.mask[tid] = 0u;
    if (tid == 0) sm.s_p33 = ((unsigned long long)1u) << 32;
    __syncthreads();
    if ((unsigned int)tid < n) {
        const int idx = (int)(0xFFFFFFFFu - (unsigned int)sm.cand[tid]);
        atomicOr(&sm.mask[idx >> 5], 1u << (idx & 31));
    }
    if (tid == 0) atomicOr(&sm.mask[row >> 5], 1u << (row & 31));
    __syncthreads();

    // scan cent[] (16 KB, L1/L2-hot: identical vector for all rows) w/ exclusion
    float cmin = INFINITY, cmax = -INFINITY;
    const float4* cp = (const float4*)cent;
#pragma unroll
    for (int c = 0; c < 4; ++c) {
        float4 q = cp[c * 256 + tid];
        const unsigned int mw = sm.mask[c * 32 + (tid >> 3)];  // broadcast read
        float t[4] = {q.x, q.y, q.z, q.w};
#pragma unroll
        for (int m = 0; m < 4; ++m) {
            const unsigned int bit = 1u << (((tid & 7) << 2) + m);
            if (!(mw & bit)) { cmin = fminf(cmin, t[m]); cmax = fmaxf(cmax, t[m]); }
        }
    }
    { float a = wave_min_f(cmin), b = wave_max_f(cmax);
      if (lane == 0) { sm.s_cmin[wid] = a; sm.s_cmax[wid] = b; } }
    __syncthreads();

    if (wid != 0) return;

    // exact all-pairs ranks, all state in named VGPRs (validated round 4)
    const unsigned int p0 = lane, p1 = lane + 64u, p2 = lane + 128u, p3 = lane + 192u;
    unsigned long long own0 = 0ull, own1 = 0ull, own2 = 0ull, own3 = 0ull;
    if (p0 < n) own0 = sm.cand[p0];
    if (p1 < n) own1 = sm.cand[p1];
    if (p2 < n) own2 = sm.cand[p2];
    if (p3 < n) own3 = sm.cand[p3];
    unsigned int r0 = 0, r1 = 0, r2 = 0, r3 = 0;
    const ulonglong2* c2 = (const ulonglong2*)sm.cand;     // broadcast b128
    const unsigned int np = n >> 1;
    for (unsigned int o = 0; o < np; ++o) {
        ulonglong2 pr = c2[o];
        r0 += (pr.x > own0) ? 1u : 0u; r0 += (pr.y > own0) ? 1u : 0u;
        r1 += (pr.x > own1) ? 1u : 0u; r1 += (pr.y > own1) ? 1u : 0u;
        r2 += (pr.x > own2) ? 1u : 0u; r2 += (pr.y > own2) ? 1u : 0u;
        r3 += (pr.x > own3) ? 1u : 0u; r3 += (pr.y > own3) ? 1u : 0u;
    }
    if (n & 1u) {
        unsigned long long x = sm.cand[n - 1u];
        r0 += (x > own0) ? 1u : 0u; r1 += (x > own1) ? 1u : 0u;
        r2 += (x > own2) ? 1u : 0u; r3 += (x > own3) ? 1u : 0u;
    }
    float cmin2 = INFINITY, cmax2 = -INFINITY;
    const unsigned int uk = (unsigned int)k;
#define HANDLE(P, OWN, R)                                                     \
    if ((P) < n) {                                                            \
        if ((R) < uk) sm.s_sel[R] = (OWN);                                    \
        else if ((R) == uk) sm.s_p33 = (OWN);                                 \
        if ((R) >= uk) {                                                      \
            const int jj = (int)(0xFFFFFFFFu - (unsigned int)(OWN));          \
            const float cv = cent[jj];                                        \
            cmin2 = fminf(cmin2, cv);                                         \
            cmax2 = fmaxf(cmax2, cv);                                         \
        }                                                                     \
    }
    HANDLE(p0, own0, r0)
    HANDLE(p1, own1, r1)
    HANDLE(p2, own2, r2)
    HANDLE(p3, own3, r3)
#undef HANDLE
    __builtin_amdgcn_wave_barrier();   // order s_sel/s_p33 writes vs reads
    cmin2 = wave_min_f(cmin2);
    cmax2 = wave_max_f(cmax2);
    const float mn_c = fminf(cmin2,
        fminf(fminf(sm.s_cmin[0], sm.s_cmin[1]), fminf(sm.s_cmin[2], sm.s_cmin[3])));
    const float mx_c = fmaxf(cmax2,
        fmaxf(fmaxf(sm.s_cmax[0], sm.s_cmax[1]), fmaxf(sm.s_cmax[2], sm.s_cmax[3])));
    const float mn_s = key_to_f(h.y);
    const float mx_s = key_to_f((unsigned int)(sm.s_p33 >> 32));

    // finale (math identical to validated round-1..4 kernels)
    const bool  act = (lane < k);
    const unsigned long long sel = act ? sm.s_sel[lane] : 0ull;
    const float sj = act ? key_to_f((unsigned int)(sel >> 32)) : -INFINITY;
    const int   j  = act ? (int)(0xFFFFFFFFu - (unsigned int)sel) : 0;
    const float cj = cent[j];

    float a = -INFINITY;
    if (act) {
        const float ns = (sj - mn_s) / (mx_s - mn_s);
        const float nc = (cj - mn_c) / (mx_c - mn_c);
        a = (ns - nc) * temp;
    }
    const float am   = wave_max_f(a);
    const float e    = act ? expf(a - am) : 0.0f;
    const float esum = wave_sum_f(e);
    const float pw   = e / esum;

    const float m2  = fmaxf(wave_max_f(sj), sdiag);
    const float ex  = act ? expf(sj - m2) : 0.0f;
    const float lse = m2 + logf(wave_sum_f(ex) + expf(sdiag - m2));

    const float num = wave_sum_f(act ? pw * (sj - lse) : 0.0f) + (sdiag - lse);
    const float den = 1.0f + wave_sum_f(pw);
    if (lane == 0) per_row[row] = -num / den;
}

// ---------------- D3: final mean over per_row -> out[0] ----------------
__global__ __launch_bounds__(256)
void reduce_kernel(const float* __restrict__ per_row, float* __restrict__ out, int B) {
    __shared__ float s[4];
    float acc = 0.0f;
    const float4* p = (const float4*)per_row;
    const int n4 = B >> 2;
    for (int i = threadIdx.x; i < n4; i += 256) {
        float4 q = p[i];
        acc += (q.x + q.y) + (q.z + q.w);
    }
    acc = wave_sum_f(acc);
    const int lane = threadIdx.x & 63, wid = threadIdx.x >> 6;
    if (lane == 0) s[wid] = acc;
    __syncthreads();
    if (threadIdx.x == 0) out[0] = (s[0] + s[1] + s[2] + s[3]) / (float)B;
}

extern "C" void kernel_launch(void* const* d_in, const int* in_sizes, int n_in,
                              void* d_out, int out_size, void* d_ws, size_t ws_size,
                              hipStream_t stream) {
    const float* sim  = (const float*)d_in[0];
    const float* mem  = (const float*)d_in[1];
    const int*   knn  = (const int*)d_in[2];
    const float* temp = (const float*)d_in[3];
    float* out = (float*)d_out;

    // ws layout: cent[4096]f @0 | per_row[4096]f @16K |
    //            hdr[4096]uint4 @40K | candG[4096*CAP]u64 @104K (~8 MB)
    char* base = (char*)d_ws;
    float* cent    = (float*)base;
    float* per_row = (float*)(base + 16384);
    uint4* hdr = (uint4*)(base + 40960);
    unsigned long long* candG = (unsigned long long*)(base + 40960 + 65536);

    const int B = (int)(std::sqrt((double)in_sizes[0]) + 0.5);
    const int M = in_sizes[1] / B;

    prep_kernel<<<2 * B, 256, 0, stream>>>(sim, mem, knn, cent, hdr, candG, B, M);
    loss_kernel<<<B, 256, 0, stream>>>(cent, hdr, candG, knn, temp, per_row, B);
    reduce_kernel<<<1, 256, 0, stream>>>(per_row, out, B);
}